// Round 2
// baseline (1550.762 us; speedup 1.0000x reference)
//
#include <hip/hip_runtime.h>

typedef unsigned int u32;
typedef unsigned short u16;

#define NT 128          // threads per block == edges per block
#define NB 8            // nodes per block
#define NBLK 2500       // 20000/8

// fp32 -> bf16 RNE (for LDS staging of k/v only)
__device__ __forceinline__ u16 fb(float x){
    u32 u = __float_as_uint(x);
    u += 0x7fffu + ((u>>16)&1u);
    return (u16)(u>>16);
}
__device__ __forceinline__ float bf_lo(u32 w){ return __uint_as_float(w<<16); }
__device__ __forceinline__ float bf_hi(u32 w){ return __uint_as_float(w & 0xffff0000u); }
__device__ __forceinline__ float gelu_exact(float x){
    return x*0.5f*(1.0f + erff(x*0.70710678118654752440f));
}

// ---------------- prep: transpose w2 (64x256) -> w2T (256x64) for k and v ------
__global__ void prep_w2t(const float* __restrict__ kw2, const float* __restrict__ vw2,
                         float* __restrict__ ws)
{
    int t = blockIdx.x*256 + threadIdx.x;      // 0..32767
    int half = t >> 14;
    int u = t & 16383;
    int col = u >> 6, c = u & 63;
    const float* src = half ? vw2 : kw2;
    ws[t] = src[c*256 + col];
}

// ---------------- per-edge radial MLP + tensor contraction --------------------
// h = gelu(ef@w1+b1); rw[i][j] = b2[ij] + sum_c h[c]*w2T[ij*64+c];
// t2[i] = sum_j rw[i][j]*tmp[j]; out[o][d] = sum_l t2[o*2+l]*bas2[l*4+d]
__device__ __forceinline__ void mlp_conv(
    const float* __restrict__ w1,  const float* __restrict__ b1,
    const float* __restrict__ w2T, const float* __restrict__ b2,
    const float* __restrict__ efRow,   // LDS, 32 floats (own row)
    const float* __restrict__ tmpRow,  // LDS, 16 floats (own row)
    const float* __restrict__ bas2p,   // global, 8 floats (per edge)
    u32* __restrict__ outRow)          // LDS, 16 u32 = 32 bf16 (own row)
{
    float h[64];
    #pragma unroll
    for (int c=0;c<64;c+=4){
        float4 b = *(const float4*)(b1+c);
        h[c]=b.x; h[c+1]=b.y; h[c+2]=b.z; h[c+3]=b.w;
    }
    #pragma unroll 1
    for (int x=0;x<32;++x){
        float ex = efRow[x];
        const float* wr = w1 + x*64;
        #pragma unroll
        for (int c=0;c<64;c+=4){
            float4 w = *(const float4*)(wr+c);
            h[c]   += ex*w.x; h[c+1] += ex*w.y;
            h[c+2] += ex*w.z; h[c+3] += ex*w.w;
        }
    }
    #pragma unroll
    for (int c=0;c<64;++c) h[c] = gelu_exact(h[c]);

    float4 bw0 = *(const float4*)(bas2p);      // bas2[0][0..3]
    float4 bw1 = *(const float4*)(bas2p+4);    // bas2[1][0..3]

    #pragma unroll 1
    for (int o=0;o<8;++o){
        float od0=0.f, od1=0.f, od2=0.f, od3=0.f;
        #pragma unroll
        for (int l=0;l<2;++l){
            float acc = 0.f;
            #pragma unroll 1
            for (int j=0;j<16;++j){
                const int colidx = (o*2+l)*16 + j;
                const float* col = w2T + colidx*64;
                float r0 = b2[colidx], r1=0.f, r2=0.f, r3=0.f;
                #pragma unroll
                for (int c=0;c<64;c+=16){
                    float4 wa = *(const float4*)(col+c);
                    float4 wb = *(const float4*)(col+c+4);
                    float4 wc = *(const float4*)(col+c+8);
                    float4 wd = *(const float4*)(col+c+12);
                    r0 += h[c+0]*wa.x + h[c+1]*wa.y + h[c+2]*wa.z + h[c+3]*wa.w;
                    r1 += h[c+4]*wb.x + h[c+5]*wb.y + h[c+6]*wb.z + h[c+7]*wb.w;
                    r2 += h[c+8]*wc.x + h[c+9]*wc.y + h[c+10]*wc.z + h[c+11]*wc.w;
                    r3 += h[c+12]*wd.x + h[c+13]*wd.y + h[c+14]*wd.z + h[c+15]*wd.w;
                }
                acc += ((r0+r1)+(r2+r3)) * tmpRow[j];
            }
            od0 += acc * (l==0 ? bw0.x : bw1.x);
            od1 += acc * (l==0 ? bw0.y : bw1.y);
            od2 += acc * (l==0 ? bw0.z : bw1.z);
            od3 += acc * (l==0 ? bw0.w : bw1.w);
        }
        outRow[o*2]   = (u32)fb(od0) | ((u32)fb(od1)<<16);
        outRow[o*2+1] = (u32)fb(od2) | ((u32)fb(od3)<<16);
    }
}

// ---------------- fused main kernel -------------------------------------------
__global__ __launch_bounds__(NT, 2) void eqattn_main(
    const float* __restrict__ bk1, const float* __restrict__ bk2,
    const float* __restrict__ bv1, const float* __restrict__ bv2,
    const float* __restrict__ efg, const float* __restrict__ fg,
    const float* __restrict__ qw,  const float* __restrict__ qb,
    const float* __restrict__ kw1, const float* __restrict__ kb1,
    const float* __restrict__ kb2,
    const float* __restrict__ vw1, const float* __restrict__ vb1,
    const float* __restrict__ vb2,
    const float* __restrict__ ow,  const float* __restrict__ ob,
    const int* __restrict__ nidx,  const float* __restrict__ ws,
    float* __restrict__ outg)
{
    __shared__ __align__(16) float sEF [NT*17];   // ef rows (32 f32, stride 17... 16 used? see below)
    __shared__ __align__(16) u32  sK  [NT*18];    // k rows: 32 bf16 packed in 16 u32, stride 18
    __shared__ __align__(16) u32  sTkV[NT*18];    // tmpk f32 rows -> V bf16 rows (row-private overlay)
    __shared__ __align__(16) float sTv [NT*17];   // tmpv f32 rows -> qS/lg/aoS scratch

    const int t  = threadIdx.x;
    const int n0 = blockIdx.x * NB;
    const int e  = n0*16 + t;                     // this thread's edge

    // NOTE: sEF rows need 32 floats: use stride 33 within a [NT*17 + NT*16] view is
    // wrong — so sEF is actually sized for stride 17 u32? We need 32 floats/row.
    // Use two half-rows: row t occupies sEF[t*17 .. t*17+16) for x<16 and the
    // second half lives in a separate array below.
    __shared__ __align__(16) float sEF2[NT*17];   // ef x=16..31

    float* tmpkRow = (float*)sTkV + t*18;
    float* tmpvRow = sTv + t*17;

    // ---- phase 0: gather f[src], tmpk/tmpv, stage ef ----
    {
        int src = nidx[e];
        const float4* fr = (const float4*)(fg + src*32);
        float fs[32];
        #pragma unroll
        for (int i=0;i<8;++i){
            float4 v = fr[i];
            fs[i*4]=v.x; fs[i*4+1]=v.y; fs[i*4+2]=v.z; fs[i*4+3]=v.w;
        }
        float4 ka = *(const float4*)(bk1+e*8), kbv = *(const float4*)(bk1+e*8+4);
        float4 va = *(const float4*)(bv1+e*8), vbv = *(const float4*)(bv1+e*8+4);
        float b1k[8] = {ka.x,ka.y,ka.z,ka.w,kbv.x,kbv.y,kbv.z,kbv.w};
        float b1v[8] = {va.x,va.y,va.z,va.w,vbv.x,vbv.y,vbv.z,vbv.w};
        #pragma unroll
        for (int m=0;m<8;++m){
            float t0=0.f,t1=0.f,u0=0.f,u1=0.f;
            #pragma unroll
            for (int d=0;d<4;++d){
                float fv = fs[m*4+d];
                t0 += fv*b1k[d*2];  t1 += fv*b1k[d*2+1];
                u0 += fv*b1v[d*2];  u1 += fv*b1v[d*2+1];
            }
            tmpkRow[m*2]=t0; tmpkRow[m*2+1]=t1;
            tmpvRow[m*2]=u0; tmpvRow[m*2+1]=u1;
        }
        const float4* ep = (const float4*)(efg + e*32);
        #pragma unroll
        for (int i=0;i<4;++i){
            float4 v = ep[i];
            sEF[t*17+i*4]=v.x; sEF[t*17+i*4+1]=v.y; sEF[t*17+i*4+2]=v.z; sEF[t*17+i*4+3]=v.w;
        }
        #pragma unroll
        for (int i=0;i<4;++i){
            float4 v = ep[4+i];
            sEF2[t*17+i*4]=v.x; sEF2[t*17+i*4+1]=v.y; sEF2[t*17+i*4+2]=v.z; sEF2[t*17+i*4+3]=v.w;
        }
    }

    // ef accessor rows (two halves, both stride 17, conflict-free)
    // wrap into a tiny local lambda-free approach: mlp_conv takes one pointer,
    // so copy second half adjacency via an index trick: pass both pointers.
    // Simplest: inline the two-half read by giving mlp_conv a row that it reads
    // via helper; here we emulate the old single-row contract by using a local
    // stack array is NOT allowed (dynamic x). Instead mlp_conv reads
    // efRow[x<16 ? ...], so we pass both and let it select — duplicated loop:
    // to keep mlp_conv unchanged we instead do two x-half loops inside it via
    // pointer arithmetic: ef half selected by x>>4. To avoid changing the
    // signature, we pack: efRow points at sEF + t*17 and efRow2 at sEF2 + t*17.
    // (mlp_conv below was written for a single 32-float row; we call a wrapper.)

    // ---- K conv ----
    {
        // temporary contiguous view: reuse mlp_conv with two half rows by
        // calling it on a stitched row is not possible; so call variant:
        // replicate mlp_conv body is avoided by passing sEF/sEF2 via globals.
        // => We instead call mlp_conv with efRow = sEF + t*17 and rely on the
        //    x-loop below reading the second half from sEF2 through the
        //    distance (sEF2 - sEF) being uniform. Compute that delta:
        const float* efRow  = sEF  + t*17;
        const float* efRow2 = sEF2 + t*17;
        // K
        {
            float h[64];
            #pragma unroll
            for (int c=0;c<64;c+=4){
                float4 b = *(const float4*)(kb1+c);
                h[c]=b.x; h[c+1]=b.y; h[c+2]=b.z; h[c+3]=b.w;
            }
            #pragma unroll 1
            for (int x=0;x<16;++x){
                float e0 = efRow[x], e1 = efRow2[x];
                const float* wr0 = kw1 + x*64;
                const float* wr1 = kw1 + (x+16)*64;
                #pragma unroll
                for (int c=0;c<64;c+=4){
                    float4 w0 = *(const float4*)(wr0+c);
                    float4 w1 = *(const float4*)(wr1+c);
                    h[c]   += e0*w0.x + e1*w1.x;
                    h[c+1] += e0*w0.y + e1*w1.y;
                    h[c+2] += e0*w0.z + e1*w1.z;
                    h[c+3] += e0*w0.w + e1*w1.w;
                }
            }
            #pragma unroll
            for (int c=0;c<64;++c) h[c] = gelu_exact(h[c]);
            float4 bw0 = *(const float4*)(bk2+e*8);
            float4 bw1 = *(const float4*)(bk2+e*8+4);
            u32* outRow = sK + t*18;
            #pragma unroll 1
            for (int o=0;o<8;++o){
                float od0=0.f,od1=0.f,od2=0.f,od3=0.f;
                #pragma unroll
                for (int l=0;l<2;++l){
                    float acc=0.f;
                    #pragma unroll 1
                    for (int j=0;j<16;++j){
                        const int colidx=(o*2+l)*16+j;
                        const float* col = ws + colidx*64;
                        float r0=kb2[colidx],r1=0.f,r2=0.f,r3=0.f;
                        #pragma unroll
                        for (int c=0;c<64;c+=16){
                            float4 wa=*(const float4*)(col+c);
                            float4 wb=*(const float4*)(col+c+4);
                            float4 wc=*(const float4*)(col+c+8);
                            float4 wd=*(const float4*)(col+c+12);
                            r0 += h[c+0]*wa.x+h[c+1]*wa.y+h[c+2]*wa.z+h[c+3]*wa.w;
                            r1 += h[c+4]*wb.x+h[c+5]*wb.y+h[c+6]*wb.z+h[c+7]*wb.w;
                            r2 += h[c+8]*wc.x+h[c+9]*wc.y+h[c+10]*wc.z+h[c+11]*wc.w;
                            r3 += h[c+12]*wd.x+h[c+13]*wd.y+h[c+14]*wd.z+h[c+15]*wd.w;
                        }
                        acc += ((r0+r1)+(r2+r3))*tmpkRow[j];
                    }
                    od0 += acc*(l==0?bw0.x:bw1.x);
                    od1 += acc*(l==0?bw0.y:bw1.y);
                    od2 += acc*(l==0?bw0.z:bw1.z);
                    od3 += acc*(l==0?bw0.w:bw1.w);
                }
                outRow[o*2]   = (u32)fb(od0) | ((u32)fb(od1)<<16);
                outRow[o*2+1] = (u32)fb(od2) | ((u32)fb(od3)<<16);
            }
        }
        // V (tmpv in sTv; output overlays tmpk region — row-private, no barrier)
        {
            float h[64];
            #pragma unroll
            for (int c=0;c<64;c+=4){
                float4 b = *(const float4*)(vb1+c);
                h[c]=b.x; h[c+1]=b.y; h[c+2]=b.z; h[c+3]=b.w;
            }
            #pragma unroll 1
            for (int x=0;x<16;++x){
                float e0 = efRow[x], e1 = efRow2[x];
                const float* wr0 = vw1 + x*64;
                const float* wr1 = vw1 + (x+16)*64;
                #pragma unroll
                for (int c=0;c<64;c+=4){
                    float4 w0 = *(const float4*)(wr0+c);
                    float4 w1 = *(const float4*)(wr1+c);
                    h[c]   += e0*w0.x + e1*w1.x;
                    h[c+1] += e0*w0.y + e1*w1.y;
                    h[c+2] += e0*w0.z + e1*w1.z;
                    h[c+3] += e0*w0.w + e1*w1.w;
                }
            }
            #pragma unroll
            for (int c=0;c<64;++c) h[c] = gelu_exact(h[c]);
            float4 bw0 = *(const float4*)(bv2+e*8);
            float4 bw1 = *(const float4*)(bv2+e*8+4);
            // V results: pack into registers first, then overwrite tmpk row
            u32 vout[16];
            #pragma unroll 1
            for (int o=0;o<8;++o){
                float od0=0.f,od1=0.f,od2=0.f,od3=0.f;
                #pragma unroll
                for (int l=0;l<2;++l){
                    float acc=0.f;
                    #pragma unroll 1
                    for (int j=0;j<16;++j){
                        const int colidx=(o*2+l)*16+j;
                        const float* col = ws + 16384 + colidx*64;
                        float r0=vb2[colidx],r1=0.f,r2=0.f,r3=0.f;
                        #pragma unroll
                        for (int c=0;c<64;c+=16){
                            float4 wa=*(const float4*)(col+c);
                            float4 wb=*(const float4*)(col+c+4);
                            float4 wc=*(const float4*)(col+c+8);
                            float4 wd=*(const float4*)(col+c+12);
                            r0 += h[c+0]*wa.x+h[c+1]*wa.y+h[c+2]*wa.z+h[c+3]*wa.w;
                            r1 += h[c+4]*wb.x+h[c+5]*wb.y+h[c+6]*wb.z+h[c+7]*wb.w;
                            r2 += h[c+8]*wc.x+h[c+9]*wc.y+h[c+10]*wc.z+h[c+11]*wc.w;
                            r3 += h[c+12]*wd.x+h[c+13]*wd.y+h[c+14]*wd.z+h[c+15]*wd.w;
                        }
                        acc += ((r0+r1)+(r2+r3))*tmpvRow[j];
                    }
                    od0 += acc*(l==0?bw0.x:bw1.x);
                    od1 += acc*(l==0?bw0.y:bw1.y);
                    od2 += acc*(l==0?bw0.z:bw1.z);
                    od3 += acc*(l==0?bw0.w:bw1.w);
                }
                vout[o*2]   = (u32)fb(od0) | ((u32)fb(od1)<<16);
                vout[o*2+1] = (u32)fb(od2) | ((u32)fb(od3)<<16);
            }
            u32* vRow = sTkV + t*18;
            #pragma unroll
            for (int i=0;i<16;++i) vRow[i] = vout[i];
        }
    }
    __syncthreads();    // all k/v rows visible; tmpv region now reusable

    float* qS  = sTv;          // [8][33] = 264 floats
    float* lg  = sTv + 264;    // [32][17] = 544 floats
    float* aoS = sTv + 808;    // [8][33] = 264 floats

    // ---- q = eq_linear(f, q_w, q_b): 256 tasks (ln,m,d) ----
    #pragma unroll 1
    for (int p=0;p<2;++p){
        int task = p*NT + t;
        int ln = task>>5, m=(task>>2)&7, d=task&3;
        const float* frow = fg + (n0+ln)*32;
        int r = ((d>0)?8:0) + m;
        float acc = (d==0) ? qb[m] : 0.f;
        #pragma unroll
        for (int mm=0;mm<8;++mm) acc += qw[r*8+mm]*frow[mm*4+d];
        qS[ln*33 + m*4 + d] = acc;
    }
    __syncthreads();

    // ---- logits: 512 tasks (ln,h,k) ----
    #pragma unroll 1
    for (int p=0;p<4;++p){
        int task = p*NT + t;
        int ln = task>>6, hh=(task>>4)&3, k=task&15;
        const u32* kr = sK + (ln*16+k)*18 + hh*4;
        const float* qr = qS + ln*33 + hh*8;
        float acc=0.f;
        #pragma unroll
        for (int c=0;c<4;++c){
            u32 w = kr[c];
            acc += qr[c*2]*bf_lo(w) + qr[c*2+1]*bf_hi(w);
        }
        lg[(ln*4+hh)*17 + k] = acc * 0.35355339059327373f;
    }
    __syncthreads();

    // ---- softmax over 16 neighbors: 32 rows ----
    if (t < 32){
        float* row = lg + t*17;
        float mx = row[0];
        #pragma unroll
        for (int k=1;k<16;++k) mx = fmaxf(mx, row[k]);
        float ev[16]; float s=0.f;
        #pragma unroll
        for (int k=0;k<16;++k){ ev[k] = __expf(row[k]-mx); s += ev[k]; }
        float inv = 1.f/s;
        #pragma unroll
        for (int k=0;k<16;++k) row[k] = ev[k]*inv;
    }
    __syncthreads();

    // ---- attention output: 256 tasks (ln,comp) ----
    #pragma unroll 1
    for (int p=0;p<2;++p){
        int task = p*NT + t;
        int ln = task>>5, comp = task&31, hh = comp>>3;
        const float* ar = lg + (ln*4+hh)*17;
        float acc=0.f;
        #pragma unroll
        for (int k=0;k<16;++k){
            u32 w = sTkV[(ln*16+k)*18 + (comp>>1)];
            acc += ar[k] * ((comp&1) ? bf_hi(w) : bf_lo(w));
        }
        aoS[ln*33 + comp] = acc;
    }
    __syncthreads();

    // ---- final eq_linear(o_w, o_b) -> fp32 out ----
    #pragma unroll 1
    for (int p=0;p<2;++p){
        int task = p*NT + t;
        int ln = task>>5, m=(task>>2)&7, d=task&3;
        int r = ((d>0)?8:0) + m;
        float acc = (d==0) ? ob[m] : 0.f;
        #pragma unroll
        for (int mm=0;mm<8;++mm) acc += ow[r*8+mm]*aoS[ln*33 + mm*4 + d];
        outg[(n0+ln)*32 + m*4 + d] = acc;
    }
}

extern "C" void kernel_launch(void* const* d_in, const int* in_sizes, int n_in,
                              void* d_out, int out_size, void* d_ws, size_t ws_size,
                              hipStream_t stream)
{
    (void)in_sizes; (void)n_in; (void)out_size; (void)ws_size;
    const float* bk1 = (const float*)d_in[0];
    const float* bk2 = (const float*)d_in[1];
    const float* bv1 = (const float*)d_in[2];
    const float* bv2 = (const float*)d_in[3];
    const float* efg = (const float*)d_in[4];
    const float* fg  = (const float*)d_in[5];
    const float* qw  = (const float*)d_in[6];
    const float* qb  = (const float*)d_in[7];
    const float* kw1 = (const float*)d_in[8];
    const float* kb1 = (const float*)d_in[9];
    const float* kw2 = (const float*)d_in[10];
    const float* kb2 = (const float*)d_in[11];
    const float* vw1 = (const float*)d_in[12];
    const float* vb1 = (const float*)d_in[13];
    const float* vw2 = (const float*)d_in[14];
    const float* vb2 = (const float*)d_in[15];
    const float* ow  = (const float*)d_in[16];
    const float* ob  = (const float*)d_in[17];
    const int* nidx  = (const int*)d_in[18];
    float* ws = (float*)d_ws;

    prep_w2t<<<128, 256, 0, stream>>>(kw2, vw2, ws);
    eqattn_main<<<NBLK, NT, 0, stream>>>(
        bk1,bk2,bv1,bv2, efg, fg, qw,qb, kw1,kb1,kb2, vw1,vb1,vb2,
        ow,ob, nidx, ws, (float*)d_out);
}

// Round 3
// 1274.404 us; speedup vs baseline: 1.2169x; 1.2169x over previous
//
#include <hip/hip_runtime.h>

typedef unsigned int u32;
typedef unsigned short u16;

#define NT 128          // threads per block == edges per block
#define NB 8            // nodes per block
#define NBLK 2500       // 20000/8

// fp32 -> bf16 RNE (LDS staging of k/v only)
__device__ __forceinline__ u16 fb(float x){
    u32 u = __float_as_uint(x);
    u += 0x7fffu + ((u>>16)&1u);
    return (u16)(u>>16);
}
__device__ __forceinline__ float bf_lo(u32 w){ return __uint_as_float(w<<16); }
__device__ __forceinline__ float bf_hi(u32 w){ return __uint_as_float(w & 0xffff0000u); }
__device__ __forceinline__ float gelu_exact(float x){
    return x*0.5f*(1.0f + erff(x*0.70710678118654752440f));
}

// ---------------- prep: transpose w2 (64x256) -> w2T (256x64) for k and v ------
__global__ void prep_w2t(const float* __restrict__ kw2, const float* __restrict__ vw2,
                         float* __restrict__ ws)
{
    int t = blockIdx.x*256 + threadIdx.x;      // 0..32767
    int half = t >> 14;
    int u = t & 16383;
    int col = u >> 6, c = u & 63;
    const float* src = half ? vw2 : kw2;
    ws[t] = src[c*256 + col];
}

// 64-deep dot product of h (regs) with a w2T column, 4 independent chains
__device__ __forceinline__ float dot64(const float* __restrict__ col,
                                       const float* __restrict__ h, float init)
{
    float r0=init, r1=0.f, r2=0.f, r3=0.f;
    #pragma unroll
    for (int c=0;c<64;c+=16){
        float4 a = *(const float4*)(col+c);
        float4 b = *(const float4*)(col+c+4);
        float4 g = *(const float4*)(col+c+8);
        float4 d = *(const float4*)(col+c+12);
        r0 += h[c+0]*a.x + h[c+1]*a.y + h[c+2]*a.z + h[c+3]*a.w;
        r1 += h[c+4]*b.x + h[c+5]*b.y + h[c+6]*b.z + h[c+7]*b.w;
        r2 += h[c+8]*g.x + h[c+9]*g.y + h[c+10]*g.z + h[c+11]*g.w;
        r3 += h[c+12]*d.x + h[c+13]*d.y + h[c+14]*d.z + h[c+15]*d.w;
    }
    return (r0+r1)+(r2+r3);
}

// One radial-MLP conv for one edge: h=gelu(ef@w1+b1); t2=(b2+h@w2T)·tmp;
// out[o][d] = sum_l t2[o*2+l]*bas2[l*4+d], packed to bf16 pairs in outw[16].
__device__ __forceinline__ void conv_one(
    const float* __restrict__ w1,  const float* __restrict__ b1,
    const float* __restrict__ w2T, const float* __restrict__ b2,
    const float* __restrict__ efG,     // global, 32 floats (this edge)
    const float* __restrict__ tmpRow,  // LDS, 16 floats (own row)
    const float* __restrict__ bas2p,   // global, 8 floats (this edge)
    u32* __restrict__ outw)            // 16 u32 (regs)
{
    float h[64];
    #pragma unroll
    for (int c=0;c<64;c+=4){
        float4 b = *(const float4*)(b1+c);
        h[c]=b.x; h[c+1]=b.y; h[c+2]=b.z; h[c+3]=b.w;
    }
    #pragma unroll 1
    for (int xg=0; xg<8; ++xg){
        float4 ev = *(const float4*)(efG + xg*4);   // per-edge, L1-hot 2nd pass
        const float* wr = w1 + xg*256;
        float e0=ev.x, e1=ev.y, e2=ev.z, e3=ev.w;
        #pragma unroll
        for (int c=0;c<64;c+=4){
            float4 w0 = *(const float4*)(wr+c);
            float4 w1v= *(const float4*)(wr+64+c);
            float4 w2v= *(const float4*)(wr+128+c);
            float4 w3v= *(const float4*)(wr+192+c);
            h[c]   += e0*w0.x + e1*w1v.x + e2*w2v.x + e3*w3v.x;
            h[c+1] += e0*w0.y + e1*w1v.y + e2*w2v.y + e3*w3v.y;
            h[c+2] += e0*w0.z + e1*w1v.z + e2*w2v.z + e3*w3v.z;
            h[c+3] += e0*w0.w + e1*w1v.w + e2*w2v.w + e3*w3v.w;
        }
    }
    #pragma unroll
    for (int c=0;c<64;++c) h[c] = gelu_exact(h[c]);

    float4 bw0 = *(const float4*)(bas2p);
    float4 bw1 = *(const float4*)(bas2p+4);

    #pragma unroll 1
    for (int o=0;o<8;++o){
        const int base0 = (o*2)*16, base1 = (o*2+1)*16;
        float t20=0.f, t21=0.f;
        #pragma unroll 1
        for (int j=0;j<16;j+=2){
            float tj0 = tmpRow[j], tj1 = tmpRow[j+1];
            // 4 independent 64-deep dots -> ~64 loads in flight
            float a0 = dot64(w2T+(base0+j  )*64, h, b2[base0+j  ]);
            float a1 = dot64(w2T+(base0+j+1)*64, h, b2[base0+j+1]);
            float c0 = dot64(w2T+(base1+j  )*64, h, b2[base1+j  ]);
            float c1 = dot64(w2T+(base1+j+1)*64, h, b2[base1+j+1]);
            t20 += a0*tj0 + a1*tj1;
            t21 += c0*tj0 + c1*tj1;
        }
        float od0 = t20*bw0.x + t21*bw1.x;
        float od1 = t20*bw0.y + t21*bw1.y;
        float od2 = t20*bw0.z + t21*bw1.z;
        float od3 = t20*bw0.w + t21*bw1.w;
        outw[o*2]   = (u32)fb(od0) | ((u32)fb(od1)<<16);
        outw[o*2+1] = (u32)fb(od2) | ((u32)fb(od3)<<16);
    }
}

// ---------------- fused main kernel -------------------------------------------
__global__ __launch_bounds__(NT, 3) void eqattn_main(
    const float* __restrict__ bk1, const float* __restrict__ bk2,
    const float* __restrict__ bv1, const float* __restrict__ bv2,
    const float* __restrict__ efg, const float* __restrict__ fg,
    const float* __restrict__ qw,  const float* __restrict__ qb,
    const float* __restrict__ kw1, const float* __restrict__ kb1,
    const float* __restrict__ kb2,
    const float* __restrict__ vw1, const float* __restrict__ vb1,
    const float* __restrict__ vb2,
    const float* __restrict__ ow,  const float* __restrict__ ob,
    const int* __restrict__ nidx,  const float* __restrict__ ws,
    float* __restrict__ outg)
{
    __shared__ __align__(16) u32   sK  [NT*18];   // k rows: 32 bf16 in 16 u32, stride 18
    __shared__ __align__(16) u32   sTkV[NT*18];   // tmpk f32 rows -> V bf16 rows (row-private overlay)
    __shared__ __align__(16) float sTv [NT*17];   // tmpv f32 rows -> qS/lg/aoS scratch
    // total LDS = 27136 B -> 6 blocks/CU

    const int t  = threadIdx.x;
    const int n0 = blockIdx.x * NB;
    const int e  = n0*16 + t;                     // this thread's edge

    float* tmpkRow = (float*)(sTkV + t*18);
    float* tmpvRow = sTv + t*17;

    // ---- phase 0: gather f[src], compute tmpk/tmpv ----
    {
        int src = nidx[e];
        const float4* fr = (const float4*)(fg + src*32);
        float fs[32];
        #pragma unroll
        for (int i=0;i<8;++i){
            float4 v = fr[i];
            fs[i*4]=v.x; fs[i*4+1]=v.y; fs[i*4+2]=v.z; fs[i*4+3]=v.w;
        }
        float4 ka = *(const float4*)(bk1+e*8), kbv = *(const float4*)(bk1+e*8+4);
        float4 va = *(const float4*)(bv1+e*8), vbv = *(const float4*)(bv1+e*8+4);
        float b1k[8] = {ka.x,ka.y,ka.z,ka.w,kbv.x,kbv.y,kbv.z,kbv.w};
        float b1v[8] = {va.x,va.y,va.z,va.w,vbv.x,vbv.y,vbv.z,vbv.w};
        #pragma unroll
        for (int m=0;m<8;++m){
            float t0=0.f,t1=0.f,u0=0.f,u1=0.f;
            #pragma unroll
            for (int d=0;d<4;++d){
                float fv = fs[m*4+d];
                t0 += fv*b1k[d*2];  t1 += fv*b1k[d*2+1];
                u0 += fv*b1v[d*2];  u1 += fv*b1v[d*2+1];
            }
            tmpkRow[m*2]=t0; tmpkRow[m*2+1]=t1;
            tmpvRow[m*2]=u0; tmpvRow[m*2+1]=u1;
        }
    }

    // ---- K conv ----
    {
        u32 kout[16];
        conv_one(kw1, kb1, ws, kb2, efg + e*32, tmpkRow, bk2 + e*8, kout);
        u32* kRow = sK + t*18;
        #pragma unroll
        for (int i=0;i<16;++i) kRow[i] = kout[i];
    }
    // ---- V conv (output overlays tmpk row — row-private, no barrier) ----
    {
        u32 vout[16];
        conv_one(vw1, vb1, ws + 16384, vb2, efg + e*32, tmpvRow, bv2 + e*8, vout);
        u32* vRow = sTkV + t*18;
        #pragma unroll
        for (int i=0;i<16;++i) vRow[i] = vout[i];
    }
    __syncthreads();    // all k/v rows visible; tmpv region now reusable

    float* qS  = sTv;          // [8][33] = 264 floats
    float* lg  = sTv + 264;    // [32][17] = 544 floats
    float* aoS = sTv + 808;    // [8][33] = 264 floats

    // ---- q = eq_linear(f, q_w, q_b): 256 tasks (ln,m,d) ----
    #pragma unroll 1
    for (int p=0;p<2;++p){
        int task = p*NT + t;
        int ln = task>>5, m=(task>>2)&7, d=task&3;
        const float* frow = fg + (n0+ln)*32;
        int r = ((d>0)?8:0) + m;
        float acc = (d==0) ? qb[m] : 0.f;
        #pragma unroll
        for (int mm=0;mm<8;++mm) acc += qw[r*8+mm]*frow[mm*4+d];
        qS[ln*33 + m*4 + d] = acc;
    }
    __syncthreads();

    // ---- logits: 512 tasks (ln,h,k) ----
    #pragma unroll 1
    for (int p=0;p<4;++p){
        int task = p*NT + t;
        int ln = task>>6, hh=(task>>4)&3, k=task&15;
        const u32* kr = sK + (ln*16+k)*18 + hh*4;
        const float* qr = qS + ln*33 + hh*8;
        float acc=0.f;
        #pragma unroll
        for (int c=0;c<4;++c){
            u32 w = kr[c];
            acc += qr[c*2]*bf_lo(w) + qr[c*2+1]*bf_hi(w);
        }
        lg[(ln*4+hh)*17 + k] = acc * 0.35355339059327373f;
    }
    __syncthreads();

    // ---- softmax over 16 neighbors: 32 rows ----
    if (t < 32){
        float* row = lg + t*17;
        float mx = row[0];
        #pragma unroll
        for (int k=1;k<16;++k) mx = fmaxf(mx, row[k]);
        float ev[16]; float s=0.f;
        #pragma unroll
        for (int k=0;k<16;++k){ ev[k] = __expf(row[k]-mx); s += ev[k]; }
        float inv = 1.f/s;
        #pragma unroll
        for (int k=0;k<16;++k) row[k] = ev[k]*inv;
    }
    __syncthreads();

    // ---- attention output: 256 tasks (ln,comp) ----
    #pragma unroll 1
    for (int p=0;p<2;++p){
        int task = p*NT + t;
        int ln = task>>5, comp = task&31, hh = comp>>3;
        const float* ar = lg + (ln*4+hh)*17;
        float acc=0.f;
        #pragma unroll
        for (int k=0;k<16;++k){
            u32 w = sTkV[(ln*16+k)*18 + (comp>>1)];
            acc += ar[k] * ((comp&1) ? bf_hi(w) : bf_lo(w));
        }
        aoS[ln*33 + comp] = acc;
    }
    __syncthreads();

    // ---- final eq_linear(o_w, o_b) -> fp32 out ----
    #pragma unroll 1
    for (int p=0;p<2;++p){
        int task = p*NT + t;
        int ln = task>>5, m=(task>>2)&7, d=task&3;
        int r = ((d>0)?8:0) + m;
        float acc = (d==0) ? ob[m] : 0.f;
        #pragma unroll
        for (int mm=0;mm<8;++mm) acc += ow[r*8+mm]*aoS[ln*33 + mm*4 + d];
        outg[(n0+ln)*32 + m*4 + d] = acc;
    }
}

extern "C" void kernel_launch(void* const* d_in, const int* in_sizes, int n_in,
                              void* d_out, int out_size, void* d_ws, size_t ws_size,
                              hipStream_t stream)
{
    (void)in_sizes; (void)n_in; (void)out_size; (void)ws_size;
    const float* bk1 = (const float*)d_in[0];
    const float* bk2 = (const float*)d_in[1];
    const float* bv1 = (const float*)d_in[2];
    const float* bv2 = (const float*)d_in[3];
    const float* efg = (const float*)d_in[4];
    const float* fg  = (const float*)d_in[5];
    const float* qw  = (const float*)d_in[6];
    const float* qb  = (const float*)d_in[7];
    const float* kw1 = (const float*)d_in[8];
    const float* kb1 = (const float*)d_in[9];
    const float* kw2 = (const float*)d_in[10];
    const float* kb2 = (const float*)d_in[11];
    const float* vw1 = (const float*)d_in[12];
    const float* vb1 = (const float*)d_in[13];
    const float* vw2 = (const float*)d_in[14];
    const float* vb2 = (const float*)d_in[15];
    const float* ow  = (const float*)d_in[16];
    const float* ob  = (const float*)d_in[17];
    const int* nidx  = (const int*)d_in[18];
    float* ws = (float*)d_ws;

    prep_w2t<<<128, 256, 0, stream>>>(kw2, vw2, ws);
    eqattn_main<<<NBLK, NT, 0, stream>>>(
        bk1,bk2,bv1,bv2, efg, fg, qw,qb, kw1,kb1,kb2, vw1,vb1,vb2,
        ow,ob, nidx, ws, (float*)d_out);
}

// Round 4
// 330.556 us; speedup vs baseline: 4.6914x; 3.8553x over previous
//
#include <hip/hip_runtime.h>

typedef unsigned int u32;
typedef unsigned short u16;

#define NT 128
#define NBLK 2500

typedef __attribute__((ext_vector_type(8))) short bh8;
typedef __attribute__((ext_vector_type(4))) float f4;
union U8 { uint4 u; bh8 h; };

__device__ __forceinline__ u16 fb(float x){            // fp32->bf16 RNE
    u32 u = __float_as_uint(x);
    u += 0x7fffu + ((u>>16)&1u);
    return (u16)(u>>16);
}
__device__ __forceinline__ u32 pk2(float a, float b){
    return (u32)fb(a) | ((u32)fb(b)<<16);
}
__device__ __forceinline__ float bf_lo(u32 w){ return __uint_as_float(w<<16); }
__device__ __forceinline__ float bf_hi(u32 w){ return __uint_as_float(w & 0xffff0000u); }

// gelu via A&S 7.1.26 erf (|err|<=1.5e-7), branchless
__device__ __forceinline__ float gelu(float x){
    float z = fabsf(x) * 0.70710678118654752f;
    float t = 1.0f / (1.0f + 0.3275911f * z);
    float e = __expf(-z*z);
    float poly = t*(0.254829592f + t*(-0.284496736f + t*(1.421413741f +
                 t*(-1.453152027f + t*1.061405429f))));
    float erfz = 1.0f - poly*e;                       // erf(|z|) >= 0
    u32 s = (__float_as_uint(erfz) & 0x7fffffffu) | (__float_as_uint(x) & 0x80000000u);
    return 0.5f*x*(1.0f + __uint_as_float(s));
}

// ---------- prep: pack W1^T / W2^T (k and v) into MFMA A-frag order, bf16 ----
// ws16 layout (u16): [A1K:2048][A1V:2048][A2K:16384][A2V:16384]
// A1 frag (mt,lane,j): A1[m][k]=W1[k][m], m=mt*16+(lane&15), k=(lane>>4)*8+j
// A2 frag (mt,s,lane,j): A2[ij][c]=W2[c][ij], ij=mt*16+(lane&15), c=s*32+(lane>>4)*8+j
__global__ void prep_pack(const float* __restrict__ kw1, const float* __restrict__ vw1,
                          const float* __restrict__ kw2, const float* __restrict__ vw2,
                          u16* __restrict__ ws16)
{
    int t = blockIdx.x*256 + threadIdx.x;        // 0..36863
    if (t >= 36864) return;
    float val;
    if (t < 4096){
        const float* w1 = (t < 2048) ? kw1 : vw1;
        int u = t & 2047;
        int mt = u >> 9, lane = (u>>3)&63, j = u&7;
        int m = mt*16 + (lane&15);
        int x = (lane>>4)*8 + j;
        val = w1[x*64 + m];
    } else {
        int s2 = t - 4096;
        const float* w2 = (s2 < 16384) ? kw2 : vw2;
        int u = s2 & 16383;
        int blkidx = u >> 9;                      // mt*2+s
        int mt = blkidx >> 1, s = blkidx & 1;
        int lane = (u>>3)&63, j = u&7;
        int ij = mt*16 + (lane&15);
        int c  = s*32 + (lane>>4)*8 + j;
        val = w2[c*256 + ij];
    }
    ws16[t] = fb(val);
}

// ---------- one radial conv via MFMA: t2[16] stays in registers ------------
__device__ __forceinline__ void conv_mfma(
    const u16* __restrict__ pA1, const u16* __restrict__ pA2,
    const float* __restrict__ b1g, const float* __restrict__ b2g,
    const bh8* __restrict__ B1f,          // [4] cached ef frags
    const u32* __restrict__ tmpS,         // stride 10 u32 rows (16 bf16)
    u16* __restrict__ hT,                 // this wave's H-tile, stride 72 u16
    float* __restrict__ t2v,              // [16] regs out
    int w, int lane)
{
    const int r = lane & 15, q = lane >> 4;
    bh8 b2f0[4], b2f1[4];
    float tm[4][4];

    // ---- staging: per nt: MFMA1 -> gelu -> hTile -> B2 frags + tmp frags ----
    #pragma unroll
    for (int nt=0; nt<4; ++nt){
        const int ntg = w*4 + nt;
        #pragma unroll
        for (int mt=0; mt<4; ++mt){
            bh8 a1 = *(const bh8*)(pA1 + ((mt*64 + lane)<<3));
            f4 d1 = {0.f,0.f,0.f,0.f};
            d1 = __builtin_amdgcn_mfma_f32_16x16x32_bf16(a1, B1f[nt], d1, 0,0,0);
            float4 bv = *(const float4*)(b1g + mt*16 + q*4);
            float g0 = gelu(d1[0]+bv.x), g1 = gelu(d1[1]+bv.y);
            float g2 = gelu(d1[2]+bv.z), g3 = gelu(d1[3]+bv.w);
            uint2 pk; pk.x = pk2(g0,g1); pk.y = pk2(g2,g3);
            *(uint2*)(hT + r*72 + mt*16 + q*4) = pk;
        }
        __asm__ volatile("s_waitcnt lgkmcnt(0)" ::: "memory");
        b2f0[nt] = *(const bh8*)(hT + r*72 +      q*8);   // chans q*8..+7
        b2f1[nt] = *(const bh8*)(hT + r*72 + 32 + q*8);   // chans 32+q*8..+7
        uint2 tp = *(const uint2*)(tmpS + (ntg*16 + r)*10 + q*2);
        tm[nt][0]=bf_lo(tp.x); tm[nt][1]=bf_hi(tp.x);
        tm[nt][2]=bf_lo(tp.y); tm[nt][3]=bf_hi(tp.y);
        __asm__ volatile("s_waitcnt lgkmcnt(0)" ::: "memory");
    }

    // ---- main: RW^T tiles (M=ij, N=edges) + fused tmp contraction ----------
    #pragma unroll
    for (int mt=0; mt<16; ++mt){
        bh8 a2s0 = *(const bh8*)(pA2 + (((mt*2+0)*64 + lane)<<3));
        bh8 a2s1 = *(const bh8*)(pA2 + (((mt*2+1)*64 + lane)<<3));
        float4 bv = *(const float4*)(b2g + mt*16 + q*4);
        #pragma unroll
        for (int nt=0; nt<4; ++nt){
            f4 acc = {0.f,0.f,0.f,0.f};
            acc = __builtin_amdgcn_mfma_f32_16x16x32_bf16(a2s0, b2f0[nt], acc, 0,0,0);
            acc = __builtin_amdgcn_mfma_f32_16x16x32_bf16(a2s1, b2f1[nt], acc, 0,0,0);
            // lane holds rw[e][mt*16+q*4+reg] for edge e=(w*4+nt)*16+r
            float p = (acc[0]+bv.x)*tm[nt][0] + (acc[1]+bv.y)*tm[nt][1]
                    + (acc[2]+bv.z)*tm[nt][2] + (acc[3]+bv.w)*tm[nt][3];
            p += __shfl_xor(p, 16);
            p += __shfl_xor(p, 32);
            if (q == nt) t2v[mt] = p;   // owner lane of edge nt*16+r is (q=nt,r)
        }
    }
}

// ---------------- fused main kernel -------------------------------------------
__global__ __launch_bounds__(NT, 2) void eqattn_main(
    const float* __restrict__ bk1, const float* __restrict__ bk2,
    const float* __restrict__ bv1, const float* __restrict__ bv2,
    const float* __restrict__ efg, const float* __restrict__ fg,
    const float* __restrict__ qw,  const float* __restrict__ qb,
    const float* __restrict__ kb1, const float* __restrict__ kb2,
    const float* __restrict__ vb1, const float* __restrict__ vb2,
    const float* __restrict__ ow,  const float* __restrict__ ob,
    const int* __restrict__ nidx,  const u16* __restrict__ ws16,
    float* __restrict__ outg)
{
    __shared__ __align__(16) u32 sTmpK[1280];  // 5120: tmp-k bf16 rows (stride 10 u32) -> attn scratch
    __shared__ __align__(16) u32 sTmpV[1280];  // 5120: tmp-v bf16 rows
    __shared__ __align__(16) u32 sKS [2048];   // 8192: k rows 16 u32 (pair-swizzled)
    __shared__ __align__(16) u32 sVS [2048];   // 8192: v rows
    __shared__ __align__(16) u16 sHT [2304];   // 4608: per-wave H tiles (stride 72)

    const int t    = threadIdx.x;
    const int lane = t & 63;
    const int w    = t >> 6;
    const int r    = lane & 15, q = lane >> 4;
    const int n0   = blockIdx.x * 8;
    const int e    = blockIdx.x * 128 + t;

    const u16* pA1k = ws16;
    const u16* pA1v = ws16 + 2048;
    const u16* pA2k = ws16 + 4096;
    const u16* pA2v = ws16 + 20480;

    // ---- phase 0: gather f[src], tmpk/tmpv (bf16 rows) ----
    {
        int src = nidx[e];
        const float4* fr = (const float4*)(fg + src*32);
        float fs[32];
        #pragma unroll
        for (int i=0;i<8;++i){
            float4 v = fr[i];
            fs[i*4]=v.x; fs[i*4+1]=v.y; fs[i*4+2]=v.z; fs[i*4+3]=v.w;
        }
        float4 ka = *(const float4*)(bk1+e*8), kbv = *(const float4*)(bk1+e*8+4);
        float4 va = *(const float4*)(bv1+e*8), vbv = *(const float4*)(bv1+e*8+4);
        float b1k[8] = {ka.x,ka.y,ka.z,ka.w,kbv.x,kbv.y,kbv.z,kbv.w};
        float b1v[8] = {va.x,va.y,va.z,va.w,vbv.x,vbv.y,vbv.z,vbv.w};
        float tk[16], tv[16];
        #pragma unroll
        for (int m=0;m<8;++m){
            float t0=0.f,t1=0.f,u0=0.f,u1=0.f;
            #pragma unroll
            for (int d=0;d<4;++d){
                float fv = fs[m*4+d];
                t0 += fv*b1k[d*2];  t1 += fv*b1k[d*2+1];
                u0 += fv*b1v[d*2];  u1 += fv*b1v[d*2+1];
            }
            tk[m*2]=t0; tk[m*2+1]=t1; tv[m*2]=u0; tv[m*2+1]=u1;
        }
        #pragma unroll
        for (int i=0;i<8;++i){
            sTmpK[t*10+i] = pk2(tk[i*2], tk[i*2+1]);
            sTmpV[t*10+i] = pk2(tv[i*2], tv[i*2+1]);
        }
    }

    // ---- B1 frags: ef rows -> bf16 (shared by K and V convs) ----
    bh8 B1f[4];
    #pragma unroll
    for (int nt=0; nt<4; ++nt){
        int eg = blockIdx.x*128 + (w*4+nt)*16 + r;
        float4 ea = *(const float4*)(efg + eg*32 + q*8);
        float4 eb = *(const float4*)(efg + eg*32 + q*8 + 4);
        U8 uu;
        uu.u.x = pk2(ea.x, ea.y); uu.u.y = pk2(ea.z, ea.w);
        uu.u.z = pk2(eb.x, eb.y); uu.u.w = pk2(eb.z, eb.w);
        B1f[nt] = uu.h;
    }
    __asm__ volatile("s_waitcnt lgkmcnt(0)" ::: "memory");

    u16* hT = sHT + w*1152;

    // ---- K conv ----
    float t2k[16];
    conv_mfma(pA1k, pA2k, kb1, kb2, B1f, sTmpK, hT, t2k, w, lane);
    {
        float4 c0 = *(const float4*)(bk2 + e*8);
        float4 c1 = *(const float4*)(bk2 + e*8 + 4);
        #pragma unroll
        for (int m=0;m<8;++m){
            float t20 = t2k[2*m], t21 = t2k[2*m+1];
            uint2 pk;
            pk.x = pk2(t20*c0.x + t21*c1.x, t20*c0.y + t21*c1.y);
            pk.y = pk2(t20*c0.z + t21*c1.z, t20*c0.w + t21*c1.w);
            *(uint2*)(sKS + t*16 + ((m ^ (t&7))<<1)) = pk;
        }
    }
    // ---- V conv ----
    float t2va[16];
    conv_mfma(pA1v, pA2v, vb1, vb2, B1f, sTmpV, hT, t2va, w, lane);
    {
        float4 c0 = *(const float4*)(bv2 + e*8);
        float4 c1 = *(const float4*)(bv2 + e*8 + 4);
        #pragma unroll
        for (int m=0;m<8;++m){
            float t20 = t2va[2*m], t21 = t2va[2*m+1];
            uint2 pk;
            pk.x = pk2(t20*c0.x + t21*c1.x, t20*c0.y + t21*c1.y);
            pk.y = pk2(t20*c0.z + t21*c1.z, t20*c0.w + t21*c1.w);
            *(uint2*)(sVS + t*16 + ((m ^ (t&7))<<1)) = pk;
        }
    }
    __syncthreads();

    float* qS  = (float*)sTmpK;        // [8][33] = 264 floats
    float* lg  = (float*)sTmpK + 264;  // [32][17] = 544 floats
    float* aoS = (float*)sTmpK + 808;  // [8][33] = 264 floats

    // ---- q = eq_linear(f, q_w, q_b): 256 tasks ----
    #pragma unroll 1
    for (int p=0;p<2;++p){
        int task = p*NT + t;
        int ln = task>>5, m=(task>>2)&7, d=task&3;
        const float* frow = fg + (n0+ln)*32;
        int rr = ((d>0)?8:0) + m;
        float acc = (d==0) ? qb[m] : 0.f;
        #pragma unroll
        for (int mm=0;mm<8;++mm) acc += qw[rr*8+mm]*frow[mm*4+d];
        qS[ln*33 + m*4 + d] = acc;
    }
    __syncthreads();

    // ---- logits: 512 tasks ----
    #pragma unroll 1
    for (int p=0;p<4;++p){
        int task = p*NT + t;
        int ln = task>>6, hh=(task>>4)&3, k=task&15;
        int row = ln*16 + k;
        const float* qr = qS + ln*33 + hh*8;
        uint2 k0 = *(const uint2*)(sKS + row*16 + (((hh<<1)     ^ (row&7))<<1));
        uint2 k1 = *(const uint2*)(sKS + row*16 + ((((hh<<1)|1) ^ (row&7))<<1));
        float acc = qr[0]*bf_lo(k0.x)+qr[1]*bf_hi(k0.x)
                  + qr[2]*bf_lo(k0.y)+qr[3]*bf_hi(k0.y)
                  + qr[4]*bf_lo(k1.x)+qr[5]*bf_hi(k1.x)
                  + qr[6]*bf_lo(k1.y)+qr[7]*bf_hi(k1.y);
        lg[(ln*4+hh)*17 + k] = acc * 0.35355339059327373f;
    }
    __syncthreads();

    // ---- softmax over 16 neighbors: 32 rows ----
    if (t < 32){
        float* row = lg + t*17;
        float mx = row[0];
        #pragma unroll
        for (int k=1;k<16;++k) mx = fmaxf(mx, row[k]);
        float ev[16]; float s=0.f;
        #pragma unroll
        for (int k=0;k<16;++k){ ev[k] = __expf(row[k]-mx); s += ev[k]; }
        float inv = 1.f/s;
        #pragma unroll
        for (int k=0;k<16;++k) row[k] = ev[k]*inv;
    }
    __syncthreads();

    // ---- attention output: 256 tasks ----
    #pragma unroll 1
    for (int p=0;p<2;++p){
        int task = p*NT + t;
        int ln = task>>5, comp = task&31, hh = comp>>3;
        const float* ar = lg + (ln*4+hh)*17;
        float acc=0.f;
        #pragma unroll
        for (int k=0;k<16;++k){
            int row = ln*16 + k;
            u32 wv = sVS[row*16 + (((comp>>2) ^ (row&7))<<1) + ((comp>>1)&1)];
            acc += ar[k] * ((comp&1) ? bf_hi(wv) : bf_lo(wv));
        }
        aoS[ln*33 + comp] = acc;
    }
    __syncthreads();

    // ---- final eq_linear(o_w, o_b) -> fp32 out ----
    #pragma unroll 1
    for (int p=0;p<2;++p){
        int task = p*NT + t;
        int ln = task>>5, m=(task>>2)&7, d=task&3;
        int rr = ((d>0)?8:0) + m;
        float acc = (d==0) ? ob[m] : 0.f;
        #pragma unroll
        for (int mm=0;mm<8;++mm) acc += ow[rr*8+mm]*aoS[ln*33 + mm*4 + d];
        outg[(n0+ln)*32 + m*4 + d] = acc;
    }
}

extern "C" void kernel_launch(void* const* d_in, const int* in_sizes, int n_in,
                              void* d_out, int out_size, void* d_ws, size_t ws_size,
                              hipStream_t stream)
{
    (void)in_sizes; (void)n_in; (void)out_size; (void)ws_size;
    const float* bk1 = (const float*)d_in[0];
    const float* bk2 = (const float*)d_in[1];
    const float* bv1 = (const float*)d_in[2];
    const float* bv2 = (const float*)d_in[3];
    const float* efg = (const float*)d_in[4];
    const float* fg  = (const float*)d_in[5];
    const float* qw  = (const float*)d_in[6];
    const float* qb  = (const float*)d_in[7];
    const float* kw1 = (const float*)d_in[8];
    const float* kb1 = (const float*)d_in[9];
    const float* kw2 = (const float*)d_in[10];
    const float* kb2 = (const float*)d_in[11];
    const float* vw1 = (const float*)d_in[12];
    const float* vb1 = (const float*)d_in[13];
    const float* vw2 = (const float*)d_in[14];
    const float* vb2 = (const float*)d_in[15];
    const float* ow  = (const float*)d_in[16];
    const float* ob  = (const float*)d_in[17];
    const int* nidx  = (const int*)d_in[18];
    u16* ws16 = (u16*)d_ws;

    prep_pack<<<144, 256, 0, stream>>>(kw1, vw1, kw2, vw2, ws16);
    eqattn_main<<<NBLK, NT, 0, stream>>>(
        bk1,bk2,bv1,bv2, efg, fg, qw,qb, kb1,kb2, vb1,vb2,
        ow,ob, nidx, ws16, (float*)d_out);
}

// Round 6
// 295.957 us; speedup vs baseline: 5.2398x; 1.1169x over previous
//
#include <hip/hip_runtime.h>

typedef unsigned int u32;
typedef unsigned short u16;

#define NT 128
#define NBLK 2500

typedef __attribute__((ext_vector_type(8))) short bh8;
typedef __attribute__((ext_vector_type(4))) float f4;
union U8 { uint4 u; bh8 h; };

__device__ __forceinline__ u16 fb(float x){            // fp32->bf16 RNE
    u32 u = __float_as_uint(x);
    u += 0x7fffu + ((u>>16)&1u);
    return (u16)(u>>16);
}
__device__ __forceinline__ u32 pk2(float a, float b){
    return (u32)fb(a) | ((u32)fb(b)<<16);
}
__device__ __forceinline__ float bf_lo(u32 w){ return __uint_as_float(w<<16); }
__device__ __forceinline__ float bf_hi(u32 w){ return __uint_as_float(w & 0xffff0000u); }

// gelu via A&S 7.1.26 erf (|err|<=1.5e-7), branchless
__device__ __forceinline__ float gelu(float x){
    float z = fabsf(x) * 0.70710678118654752f;
    float t = 1.0f / (1.0f + 0.3275911f * z);
    float e = __expf(-z*z);
    float poly = t*(0.254829592f + t*(-0.284496736f + t*(1.421413741f +
                 t*(-1.453152027f + t*1.061405429f))));
    float erfz = 1.0f - poly*e;                       // erf(|z|) >= 0
    u32 s = (__float_as_uint(erfz) & 0x7fffffffu) | (__float_as_uint(x) & 0x80000000u);
    return 0.5f*x*(1.0f + __uint_as_float(s));
}

// ---------- prep: pack W1^T / W2^T (k and v) into MFMA A-frag order, bf16 ----
// ws16 layout (u16): [A1K:2048][A1V:2048][A2K:16384][A2V:16384]
__global__ void prep_pack(const float* __restrict__ kw1, const float* __restrict__ vw1,
                          const float* __restrict__ kw2, const float* __restrict__ vw2,
                          u16* __restrict__ ws16)
{
    int t = blockIdx.x*256 + threadIdx.x;        // 0..36863
    if (t >= 36864) return;
    float val;
    if (t < 4096){
        const float* w1 = (t < 2048) ? kw1 : vw1;
        int u = t & 2047;
        int mt = u >> 9, lane = (u>>3)&63, j = u&7;
        int m = mt*16 + (lane&15);
        int x = (lane>>4)*8 + j;
        val = w1[x*64 + m];
    } else {
        int s2 = t - 4096;
        const float* w2 = (s2 < 16384) ? kw2 : vw2;
        int u = s2 & 16383;
        int blkidx = u >> 9;                      // mt*2+s
        int mt = blkidx >> 1, s = blkidx & 1;
        int lane = (u>>3)&63, j = u&7;
        int ij = mt*16 + (lane&15);
        int c  = s*32 + (lane>>4)*8 + j;
        val = w2[c*256 + ij];
    }
    ws16[t] = fb(val);
}

// ---------- one radial conv via MFMA: t2[16] stays in registers ------------
// NOTE: the mt loop MUST be fully unrolled. `#pragma unroll 4` (round 5) made
// t2v dynamically indexed (scratch, exec-masked RMW) and produced WRONG results
// (absmax 1.9e-2 vs 9.8e-4). Spill is handled via launch_bounds instead.
__device__ __forceinline__ void conv_mfma(
    const u16* __restrict__ pA1, const u16* __restrict__ pA2,
    const float* __restrict__ b1g, const float* __restrict__ b2g,
    const bh8* __restrict__ B1f,          // [4] cached ef frags
    const u32* __restrict__ tmpS,         // stride 10 u32 rows (16 bf16)
    u16* __restrict__ hT,                 // this wave's H-tile, stride 72 u16
    float* __restrict__ t2v,              // [16] regs out
    int w, int lane)
{
    const int r = lane & 15, q = lane >> 4;
    bh8 b2f0[4], b2f1[4];
    float tm[4][4];

    // ---- staging: per nt: MFMA1 -> gelu -> hTile -> B2 frags + tmp frags ----
    #pragma unroll
    for (int nt=0; nt<4; ++nt){
        const int ntg = w*4 + nt;
        #pragma unroll
        for (int mt=0; mt<4; ++mt){
            bh8 a1 = *(const bh8*)(pA1 + ((mt*64 + lane)<<3));
            f4 d1 = {0.f,0.f,0.f,0.f};
            d1 = __builtin_amdgcn_mfma_f32_16x16x32_bf16(a1, B1f[nt], d1, 0,0,0);
            float4 bv = *(const float4*)(b1g + mt*16 + q*4);
            float g0 = gelu(d1[0]+bv.x), g1 = gelu(d1[1]+bv.y);
            float g2 = gelu(d1[2]+bv.z), g3 = gelu(d1[3]+bv.w);
            uint2 pk; pk.x = pk2(g0,g1); pk.y = pk2(g2,g3);
            *(uint2*)(hT + r*72 + mt*16 + q*4) = pk;
        }
        __asm__ volatile("s_waitcnt lgkmcnt(0)" ::: "memory");
        b2f0[nt] = *(const bh8*)(hT + r*72 +      q*8);   // chans q*8..+7
        b2f1[nt] = *(const bh8*)(hT + r*72 + 32 + q*8);   // chans 32+q*8..+7
        uint2 tp = *(const uint2*)(tmpS + (ntg*16 + r)*10 + q*2);
        tm[nt][0]=bf_lo(tp.x); tm[nt][1]=bf_hi(tp.x);
        tm[nt][2]=bf_lo(tp.y); tm[nt][3]=bf_hi(tp.y);
        __asm__ volatile("s_waitcnt lgkmcnt(0)" ::: "memory");
    }

    // ---- main: RW^T tiles (M=ij, N=edges) + fused tmp contraction ----------
    #pragma unroll
    for (int mt=0; mt<16; ++mt){
        bh8 a2s0 = *(const bh8*)(pA2 + (((mt*2+0)*64 + lane)<<3));
        bh8 a2s1 = *(const bh8*)(pA2 + (((mt*2+1)*64 + lane)<<3));
        float4 bv = *(const float4*)(b2g + mt*16 + q*4);
        #pragma unroll
        for (int nt=0; nt<4; ++nt){
            f4 acc = {0.f,0.f,0.f,0.f};
            acc = __builtin_amdgcn_mfma_f32_16x16x32_bf16(a2s0, b2f0[nt], acc, 0,0,0);
            acc = __builtin_amdgcn_mfma_f32_16x16x32_bf16(a2s1, b2f1[nt], acc, 0,0,0);
            float p = (acc[0]+bv.x)*tm[nt][0] + (acc[1]+bv.y)*tm[nt][1]
                    + (acc[2]+bv.z)*tm[nt][2] + (acc[3]+bv.w)*tm[nt][3];
            p += __shfl_xor(p, 16);
            p += __shfl_xor(p, 32);
            if (q == nt) t2v[mt] = p;   // owner lane of edge nt*16+r is (q=nt,r)
        }
    }
}

// ---------------- fused main kernel -------------------------------------------
// launch_bounds(128,1): min-waves=2 capped the allocator at 128 VGPRs and the
// fully-unrolled conv (~200 live regs) spilled ~950B/thread -> 305 MB HBM
// writes (round 4). Loosening to 1 gives the allocator headroom; LDS (31232B)
// still allows 4-5 blocks/CU.
__global__ __launch_bounds__(NT, 1) void eqattn_main(
    const float* __restrict__ bk1, const float* __restrict__ bk2,
    const float* __restrict__ bv1, const float* __restrict__ bv2,
    const float* __restrict__ efg, const float* __restrict__ fg,
    const float* __restrict__ qw,  const float* __restrict__ qb,
    const float* __restrict__ kb1, const float* __restrict__ kb2,
    const float* __restrict__ vb1, const float* __restrict__ vb2,
    const float* __restrict__ ow,  const float* __restrict__ ob,
    const int* __restrict__ nidx,  const u16* __restrict__ ws16,
    float* __restrict__ outg)
{
    __shared__ __align__(16) u32 sTmpK[1280];  // 5120: tmp-k bf16 rows (stride 10 u32) -> attn scratch
    __shared__ __align__(16) u32 sTmpV[1280];  // 5120: tmp-v bf16 rows
    __shared__ __align__(16) u32 sKS [2048];   // 8192: k rows 16 u32 (pair-swizzled)
    __shared__ __align__(16) u32 sVS [2048];   // 8192: v rows
    __shared__ __align__(16) u16 sHT [2304];   // 4608: per-wave H tiles (stride 72)

    const int t    = threadIdx.x;
    const int lane = t & 63;
    const int w    = t >> 6;
    const int r    = lane & 15, q = lane >> 4;
    const int n0   = blockIdx.x * 8;
    const int e    = blockIdx.x * 128 + t;

    const u16* pA1k = ws16;
    const u16* pA1v = ws16 + 2048;
    const u16* pA2k = ws16 + 4096;
    const u16* pA2v = ws16 + 20480;

    // ---- phase 0: gather f[src], tmpk/tmpv (bf16 rows) ----
    {
        int src = nidx[e];
        const float4* fr = (const float4*)(fg + src*32);
        float fs[32];
        #pragma unroll
        for (int i=0;i<8;++i){
            float4 v = fr[i];
            fs[i*4]=v.x; fs[i*4+1]=v.y; fs[i*4+2]=v.z; fs[i*4+3]=v.w;
        }
        float4 ka = *(const float4*)(bk1+e*8), kbv = *(const float4*)(bk1+e*8+4);
        float4 va = *(const float4*)(bv1+e*8), vbv = *(const float4*)(bv1+e*8+4);
        float b1k[8] = {ka.x,ka.y,ka.z,ka.w,kbv.x,kbv.y,kbv.z,kbv.w};
        float b1v[8] = {va.x,va.y,va.z,va.w,vbv.x,vbv.y,vbv.z,vbv.w};
        float tk[16], tv[16];
        #pragma unroll
        for (int m=0;m<8;++m){
            float t0=0.f,t1=0.f,u0=0.f,u1=0.f;
            #pragma unroll
            for (int d=0;d<4;++d){
                float fv = fs[m*4+d];
                t0 += fv*b1k[d*2];  t1 += fv*b1k[d*2+1];
                u0 += fv*b1v[d*2];  u1 += fv*b1v[d*2+1];
            }
            tk[m*2]=t0; tk[m*2+1]=t1; tv[m*2]=u0; tv[m*2+1]=u1;
        }
        #pragma unroll
        for (int i=0;i<8;++i){
            sTmpK[t*10+i] = pk2(tk[i*2], tk[i*2+1]);
            sTmpV[t*10+i] = pk2(tv[i*2], tv[i*2+1]);
        }
    }

    // ---- B1 frags: ef rows -> bf16 (shared by K and V convs) ----
    bh8 B1f[4];
    #pragma unroll
    for (int nt=0; nt<4; ++nt){
        int eg = blockIdx.x*128 + (w*4+nt)*16 + r;
        float4 ea = *(const float4*)(efg + eg*32 + q*8);
        float4 eb = *(const float4*)(efg + eg*32 + q*8 + 4);
        U8 uu;
        uu.u.x = pk2(ea.x, ea.y); uu.u.y = pk2(ea.z, ea.w);
        uu.u.z = pk2(eb.x, eb.y); uu.u.w = pk2(eb.z, eb.w);
        B1f[nt] = uu.h;
    }
    __asm__ volatile("s_waitcnt lgkmcnt(0)" ::: "memory");

    u16* hT = sHT + w*1152;

    // ---- K conv ----
    float t2k[16];
    conv_mfma(pA1k, pA2k, kb1, kb2, B1f, sTmpK, hT, t2k, w, lane);
    {
        float4 c0 = *(const float4*)(bk2 + e*8);
        float4 c1 = *(const float4*)(bk2 + e*8 + 4);
        #pragma unroll
        for (int m=0;m<8;++m){
            float t20 = t2k[2*m], t21 = t2k[2*m+1];
            uint2 pk;
            pk.x = pk2(t20*c0.x + t21*c1.x, t20*c0.y + t21*c1.y);
            pk.y = pk2(t20*c0.z + t21*c1.z, t20*c0.w + t21*c1.w);
            *(uint2*)(sKS + t*16 + ((m ^ (t&7))<<1)) = pk;
        }
    }
    // ---- V conv ----
    float t2va[16];
    conv_mfma(pA1v, pA2v, vb1, vb2, B1f, sTmpV, hT, t2va, w, lane);
    {
        float4 c0 = *(const float4*)(bv2 + e*8);
        float4 c1 = *(const float4*)(bv2 + e*8 + 4);
        #pragma unroll
        for (int m=0;m<8;++m){
            float t20 = t2va[2*m], t21 = t2va[2*m+1];
            uint2 pk;
            pk.x = pk2(t20*c0.x + t21*c1.x, t20*c0.y + t21*c1.y);
            pk.y = pk2(t20*c0.z + t21*c1.z, t20*c0.w + t21*c1.w);
            *(uint2*)(sVS + t*16 + ((m ^ (t&7))<<1)) = pk;
        }
    }
    __syncthreads();

    float* qS  = (float*)sTmpK;        // [8][33] = 264 floats
    float* lg  = (float*)sTmpK + 264;  // [32][17] = 544 floats
    float* aoS = (float*)sTmpK + 808;  // [8][33] = 264 floats

    // ---- q = eq_linear(f, q_w, q_b): 256 tasks ----
    #pragma unroll 1
    for (int p=0;p<2;++p){
        int task = p*NT + t;
        int ln = task>>5, m=(task>>2)&7, d=task&3;
        const float* frow = fg + (n0+ln)*32;
        int rr = ((d>0)?8:0) + m;
        float acc = (d==0) ? qb[m] : 0.f;
        #pragma unroll
        for (int mm=0;mm<8;++mm) acc += qw[rr*8+mm]*frow[mm*4+d];
        qS[ln*33 + m*4 + d] = acc;
    }
    __syncthreads();

    // ---- logits: 512 tasks ----
    #pragma unroll 1
    for (int p=0;p<4;++p){
        int task = p*NT + t;
        int ln = task>>6, hh=(task>>4)&3, k=task&15;
        int row = ln*16 + k;
        const float* qr = qS + ln*33 + hh*8;
        uint2 k0 = *(const uint2*)(sKS + row*16 + (((hh<<1)     ^ (row&7))<<1));
        uint2 k1 = *(const uint2*)(sKS + row*16 + ((((hh<<1)|1) ^ (row&7))<<1));
        float acc = qr[0]*bf_lo(k0.x)+qr[1]*bf_hi(k0.x)
                  + qr[2]*bf_lo(k0.y)+qr[3]*bf_hi(k0.y)
                  + qr[4]*bf_lo(k1.x)+qr[5]*bf_hi(k1.x)
                  + qr[6]*bf_lo(k1.y)+qr[7]*bf_hi(k1.y);
        lg[(ln*4+hh)*17 + k] = acc * 0.35355339059327373f;
    }
    __syncthreads();

    // ---- softmax over 16 neighbors: 32 rows ----
    if (t < 32){
        float* row = lg + t*17;
        float mx = row[0];
        #pragma unroll
        for (int k=1;k<16;++k) mx = fmaxf(mx, row[k]);
        float ev[16]; float s=0.f;
        #pragma unroll
        for (int k=0;k<16;++k){ ev[k] = __expf(row[k]-mx); s += ev[k]; }
        float inv = 1.f/s;
        #pragma unroll
        for (int k=0;k<16;++k) row[k] = ev[k]*inv;
    }
    __syncthreads();

    // ---- attention output: 256 tasks ----
    #pragma unroll 1
    for (int p=0;p<2;++p){
        int task = p*NT + t;
        int ln = task>>5, comp = task&31, hh = comp>>3;
        const float* ar = lg + (ln*4+hh)*17;
        float acc=0.f;
        #pragma unroll
        for (int k=0;k<16;++k){
            int row = ln*16 + k;
            u32 wv = sVS[row*16 + (((comp>>2) ^ (row&7))<<1) + ((comp>>1)&1)];
            acc += ar[k] * ((comp&1) ? bf_hi(wv) : bf_lo(wv));
        }
        aoS[ln*33 + comp] = acc;
    }
    __syncthreads();

    // ---- final eq_linear(o_w, o_b) -> fp32 out ----
    #pragma unroll 1
    for (int p=0;p<2;++p){
        int task = p*NT + t;
        int ln = task>>5, m=(task>>2)&7, d=task&3;
        int rr = ((d>0)?8:0) + m;
        float acc = (d==0) ? ob[m] : 0.f;
        #pragma unroll
        for (int mm=0;mm<8;++mm) acc += ow[rr*8+mm]*aoS[ln*33 + mm*4 + d];
        outg[(n0+ln)*32 + m*4 + d] = acc;
    }
}

extern "C" void kernel_launch(void* const* d_in, const int* in_sizes, int n_in,
                              void* d_out, int out_size, void* d_ws, size_t ws_size,
                              hipStream_t stream)
{
    (void)in_sizes; (void)n_in; (void)out_size; (void)ws_size;
    const float* bk1 = (const float*)d_in[0];
    const float* bk2 = (const float*)d_in[1];
    const float* bv1 = (const float*)d_in[2];
    const float* bv2 = (const float*)d_in[3];
    const float* efg = (const float*)d_in[4];
    const float* fg  = (const float*)d_in[5];
    const float* qw  = (const float*)d_in[6];
    const float* qb  = (const float*)d_in[7];
    const float* kw1 = (const float*)d_in[8];
    const float* kb1 = (const float*)d_in[9];
    const float* kw2 = (const float*)d_in[10];
    const float* kb2 = (const float*)d_in[11];
    const float* vw1 = (const float*)d_in[12];
    const float* vb1 = (const float*)d_in[13];
    const float* vw2 = (const float*)d_in[14];
    const float* vb2 = (const float*)d_in[15];
    const float* ow  = (const float*)d_in[16];
    const float* ob  = (const float*)d_in[17];
    const int* nidx  = (const int*)d_in[18];
    u16* ws16 = (u16*)d_ws;

    prep_pack<<<144, 256, 0, stream>>>(kw1, vw1, kw2, vw2, ws16);
    eqattn_main<<<NBLK, NT, 0, stream>>>(
        bk1,bk2,bv1,bv2, efg, fg, qw,qb, kb1,kb2, vb1,vb2,
        ow,ob, nidx, ws16, (float*)d_out);
}